// Round 5
// baseline (620.030 us; speedup 1.0000x reference)
//
#include <hip/hip_runtime.h>
#include <stdint.h>
#include <math.h>

// Problem constants
#define ROWS 4096
#define COLS 11008
#define ROWV8 1376u         // COLS/8
#define NELEM 45088768u     // ROWS*COLS
#define SUM_OFF 180355072u  // 4*NELEM  (offset of the scalar oscillated_sum)
#define EPS_F 1e-5f

#define BLOCK 256

// vec8 types (emitted as 2x dwordx4); 'u' = dword-aligned for +4B streams
typedef float    float8a __attribute__((ext_vector_type(8), aligned(32)));
typedef float    float8u __attribute__((ext_vector_type(8), aligned(4)));
typedef int      int8a   __attribute__((ext_vector_type(8), aligned(32)));
typedef unsigned uint2a  __attribute__((ext_vector_type(2), aligned(8)));

// ---------------------------------------------------------------------------
// Kernel 1: detect the on-device dtype of `frozen` (bool-u8 / int32 / fp32)
// and zero the scalar sum slot. Deterministic given fixed inputs.
// mode: 0 = byte bool, 1 = int32, 2 = float32
// P(byte-mode miss in 2048 words) = (0.95^3)^2048 ~ 1e-137.
// ---------------------------------------------------------------------------
__global__ void detect_init_kernel(const unsigned int* __restrict__ frozen_w,
                                   float* __restrict__ out_sum,
                                   int* __restrict__ mode_out) {
    __shared__ int s_f32, s_nonint;
    if (threadIdx.x == 0) { s_f32 = 0; s_nonint = 0; }
    __syncthreads();
    for (int i = threadIdx.x; i < 2048; i += blockDim.x) {
        unsigned int w = frozen_w[i];
        if (w == 0x3F800000u)      atomicOr(&s_f32, 1);
        else if (w > 1u)           atomicOr(&s_nonint, 1);
    }
    __syncthreads();
    if (threadIdx.x == 0) {
        *mode_out = s_f32 ? 2 : (s_nonint ? 0 : 1);
        *out_sum  = 0.0f;
    }
}

// ---------------------------------------------------------------------------
// Kernel 2: one row per block, 32B (vec8) per thread per stream per
// iteration. s[row] wave-uniform. NT loads/stores on all big streams.
// Bit-exact replication of the numpy fp32 forward.
// ---------------------------------------------------------------------------
__global__ __launch_bounds__(BLOCK) void lsq_main_kernel(
    const float* __restrict__ x,
    const float* __restrict__ s,
    const float* __restrict__ prev_x_int,
    const float* __restrict__ prev_switch_dir,
    const float* __restrict__ ema_osc,
    const void*  __restrict__ frozen,
    const float* __restrict__ frozen_x_int,
    const float* __restrict__ ema_x_int,
    float* __restrict__ out,
    const int* __restrict__ mode_ptr,
    float g)
{
    const int mode = *mode_ptr;

    float* __restrict__ o_out = out;
    float* __restrict__ o_pxi = out + (size_t)NELEM;
    float* __restrict__ o_psd = out + 2 * (size_t)NELEM;
    float* __restrict__ o_emo = out + 3 * (size_t)NELEM;
    float* __restrict__ o_sum = out + (size_t)SUM_OFF;
    float* __restrict__ o_frz = out + (size_t)SUM_OFF + 1;                      // +4B (dword-aligned only)
    float* __restrict__ o_fxi = out + (size_t)SUM_OFF + 1 + (size_t)NELEM;
    float* __restrict__ o_exi = out + (size_t)SUM_OFF + 1 + 2 * (size_t)NELEM;

    const unsigned r = blockIdx.x;          // row index; grid == ROWS
    const unsigned row8 = r * ROWV8;        // first vec8 of this row

    // s_scale: uniform per block. Forward value of sg(clipped - a*g) + a*g,
    // exact op order, no FMA (bit-exact vs numpy).
    const float alpha   = s[r];
    const float clipped = alpha > EPS_F ? alpha : EPS_F;
    const float ag      = __fmul_rn(alpha, g);
    const float ss      = __fadd_rn(__fsub_rn(clipped, ag), ag);

    int count = 0;
    for (unsigned j = threadIdx.x; j < ROWV8; j += BLOCK) {
        const unsigned i8   = row8 + j;     // global vec8 index
        const unsigned base = i8 * 8u;      // global element index

        float8a x8  = __builtin_nontemporal_load(reinterpret_cast<const float8a*>(x) + i8);
        float8a p8  = __builtin_nontemporal_load(reinterpret_cast<const float8a*>(prev_x_int) + i8);
        float8a d8  = __builtin_nontemporal_load(reinterpret_cast<const float8a*>(prev_switch_dir) + i8);
        float8a e8  = __builtin_nontemporal_load(reinterpret_cast<const float8a*>(ema_osc) + i8);
        float8a fx8 = __builtin_nontemporal_load(reinterpret_cast<const float8a*>(frozen_x_int) + i8);
        float8a ex8 = __builtin_nontemporal_load(reinterpret_cast<const float8a*>(ema_x_int) + i8);

        bool fzb[8];
        if (mode == 0) {
            uint2a w2 = __builtin_nontemporal_load(reinterpret_cast<const uint2a*>(frozen) + i8);
            #pragma unroll
            for (int h = 0; h < 2; ++h) {
                unsigned w = w2[h];
                fzb[h*4+0] = (w & 0x000000FFu) != 0u;
                fzb[h*4+1] = (w & 0x0000FF00u) != 0u;
                fzb[h*4+2] = (w & 0x00FF0000u) != 0u;
                fzb[h*4+3] = (w & 0xFF000000u) != 0u;
            }
        } else if (mode == 1) {
            int8a b = __builtin_nontemporal_load(reinterpret_cast<const int8a*>(frozen) + i8);
            #pragma unroll
            for (int k = 0; k < 8; ++k) fzb[k] = b[k] != 0;
        } else {
            float8a b = __builtin_nontemporal_load(reinterpret_cast<const float8a*>(frozen) + i8);
            #pragma unroll
            for (int k = 0; k < 8; ++k) fzb[k] = b[k] != 0.0f;
        }

        // Stage 1: xi (forward x_int), delta
        float xi[8], delta[8];
        #pragma unroll
        for (int k = 0; k < 8; ++k) {
            float xs = __fdiv_rn(x8[k], ss);                   // IEEE divide == numpy
            float xc = fminf(fmaxf(xs, -8.0f), 7.0f);
            float rr = rintf(xc);                              // half-to-even == np.round
            xi[k]    = fzb[k] ? fx8[k] : rr;
            delta[k] = __fsub_rn(p8[k], xi[k]);                // exact integer
        }

        // out and prev_x_int_new as soon as ready
        {
            float8a v;
            #pragma unroll
            for (int k = 0; k < 8; ++k) v[k] = __fmul_rn(xi[k], ss);
            __builtin_nontemporal_store(v, reinterpret_cast<float8a*>(o_out) + i8);
            #pragma unroll
            for (int k = 0; k < 8; ++k) v[k] = xi[k];
            __builtin_nontemporal_store(v, reinterpret_cast<float8a*>(o_pxi) + i8);
        }

        // Stage 2: switch dir / oscillation
        float sd[8], osc[8];
        #pragma unroll
        for (int k = 0; k < 8; ++k) {
            sd[k]  = (delta[k] > 0.0f) ? 1.0f : ((delta[k] < 0.0f) ? -1.0f : 0.0f);
            osc[k] = (__fmul_rn(d8[k], sd[k]) == -1.0f) ? 1.0f : 0.0f;
            count += (osc[k] != 0.0f) ? 1 : 0;
        }
        {
            float8a v;
            #pragma unroll
            for (int k = 0; k < 8; ++k) v[k] = (delta[k] != 0.0f) ? sd[k] : d8[k];
            __builtin_nontemporal_store(v, reinterpret_cast<float8a*>(o_psd) + i8);
        }

        // Stage 3: EMA oscillation + freeze decisions (unfused: feeds > 0.01)
        float emo_new[8]; bool fw[8];
        #pragma unroll
        for (int k = 0; k < 8; ++k) {
            emo_new[k] = __fadd_rn(__fmul_rn(0.01f, osc[k]), __fmul_rn(0.99f, e8[k]));
            fw[k]      = emo_new[k] > 0.01f;
        }
        {
            float8a v;
            #pragma unroll
            for (int k = 0; k < 8; ++k) v[k] = emo_new[k];
            __builtin_nontemporal_store(v, reinterpret_cast<float8a*>(o_emo) + i8);
        }
        {
            float8u v;
            #pragma unroll
            for (int k = 0; k < 8; ++k) v[k] = (fzb[k] || fw[k]) ? 1.0f : 0.0f;
            __builtin_nontemporal_store(v, reinterpret_cast<float8u*>(o_frz + base));
            #pragma unroll
            for (int k = 0; k < 8; ++k) v[k] = fw[k] ? rintf(ex8[k]) : fx8[k];
            __builtin_nontemporal_store(v, reinterpret_cast<float8u*>(o_fxi + base));
            #pragma unroll
            for (int k = 0; k < 8; ++k)
                v[k] = __fadd_rn(__fmul_rn(0.01f, xi[k]), __fmul_rn(0.99f, ex8[k]));
            __builtin_nontemporal_store(v, reinterpret_cast<float8u*>(o_exi + base));
        }
    }

    // exact integer reduction of oscillated count -> one float atomic per block
    for (int off = 32; off > 0; off >>= 1) count += __shfl_down(count, off, 64);
    __shared__ int wsum[BLOCK / 64];
    const int lane = threadIdx.x & 63;
    const int wid  = threadIdx.x >> 6;
    if (lane == 0) wsum[wid] = count;
    __syncthreads();
    if (threadIdx.x == 0) {
        int tot = 0;
        #pragma unroll
        for (int w = 0; w < BLOCK / 64; ++w) tot += wsum[w];
        atomicAdd(o_sum, (float)tot);   // integer-valued, < 2^24 -> exact & deterministic
    }
}

extern "C" void kernel_launch(void* const* d_in, const int* in_sizes, int n_in,
                              void* d_out, int out_size, void* d_ws, size_t ws_size,
                              hipStream_t stream) {
    const float* x   = (const float*)d_in[0];
    const float* s   = (const float*)d_in[1];
    const float* pxi = (const float*)d_in[2];
    const float* psd = (const float*)d_in[3];
    const float* emo = (const float*)d_in[4];
    const void*  frz = d_in[5];
    const float* fxi = (const float*)d_in[6];
    const float* exi = (const float*)d_in[7];
    float* out = (float*)d_out;
    int* mode  = (int*)d_ws;

    const float g = (float)(1.0 / sqrt((double)(7 * 11008)));  // np.float32(1/sqrt(THD_POS*IN))

    hipLaunchKernelGGL(detect_init_kernel, dim3(1), dim3(256), 0, stream,
                       (const unsigned int*)frz, out + (size_t)SUM_OFF, mode);
    hipLaunchKernelGGL(lsq_main_kernel, dim3(ROWS), dim3(BLOCK), 0, stream,
                       x, s, pxi, psd, emo, frz, fxi, exi, out, mode, g);
}

// Round 6
// 526.973 us; speedup vs baseline: 1.1766x; 1.1766x over previous
//
#include <hip/hip_runtime.h>
#include <stdint.h>
#include <math.h>

// Problem constants
#define ROWS 4096
#define COLS 11008
#define ROWVEC 2752u        // COLS/4
#define HALFVEC 1376u       // ROWVEC/2
#define NELEM 45088768u     // ROWS*COLS
#define SUM_OFF 180355072u  // 4*NELEM  (offset of the scalar oscillated_sum)
#define EPS_F 1e-5f

#define BLOCK 256
#define GRID 8192           // 2 blocks per row

// dword-aligned float4 for the +4B-offset output streams
typedef float float4u __attribute__((ext_vector_type(4), aligned(4)));
typedef float float4a __attribute__((ext_vector_type(4), aligned(16)));
typedef int   int4a   __attribute__((ext_vector_type(4), aligned(16)));

// ---------------------------------------------------------------------------
// Kernel 1: detect the on-device dtype of `frozen` (bool-u8 / int32 / fp32)
// and zero the scalar sum slot. Deterministic given fixed inputs.
// mode: 0 = byte bool, 1 = int32, 2 = float32
// ---------------------------------------------------------------------------
__global__ void detect_init_kernel(const unsigned int* __restrict__ frozen_w,
                                   float* __restrict__ out_sum,
                                   int* __restrict__ mode_out) {
    __shared__ int s_f32, s_nonint;
    if (threadIdx.x == 0) { s_f32 = 0; s_nonint = 0; }
    __syncthreads();
    for (int i = threadIdx.x; i < 2048; i += blockDim.x) {
        unsigned int w = frozen_w[i];
        if (w == 0x3F800000u)      atomicOr(&s_f32, 1);
        else if (w > 1u)           atomicOr(&s_nonint, 1);
    }
    __syncthreads();
    if (threadIdx.x == 0) {
        *mode_out = s_f32 ? 2 : (s_nonint ? 0 : 1);
        *out_sum  = 0.0f;
    }
}

// ---------------------------------------------------------------------------
// Kernel 2: half row per block (8192 blocks). s[row] wave-uniform. float4
// NT loads/stores on all big streams. Bit-exact numpy fp32 forward.
// ---------------------------------------------------------------------------
__global__ __launch_bounds__(BLOCK) void lsq_main_kernel(
    const float* __restrict__ x,
    const float* __restrict__ s,
    const float* __restrict__ prev_x_int,
    const float* __restrict__ prev_switch_dir,
    const float* __restrict__ ema_osc,
    const void*  __restrict__ frozen,
    const float* __restrict__ frozen_x_int,
    const float* __restrict__ ema_x_int,
    float* __restrict__ out,
    const int* __restrict__ mode_ptr,
    float g)
{
    const int mode = *mode_ptr;

    float* __restrict__ o_out = out;
    float* __restrict__ o_pxi = out + (size_t)NELEM;
    float* __restrict__ o_psd = out + 2 * (size_t)NELEM;
    float* __restrict__ o_emo = out + 3 * (size_t)NELEM;
    float* __restrict__ o_sum = out + (size_t)SUM_OFF;
    float* __restrict__ o_frz = out + (size_t)SUM_OFF + 1;                      // +4B (dword-aligned only)
    float* __restrict__ o_fxi = out + (size_t)SUM_OFF + 1 + (size_t)NELEM;
    float* __restrict__ o_exi = out + (size_t)SUM_OFF + 1 + 2 * (size_t)NELEM;

    const unsigned r    = blockIdx.x >> 1;                 // row index
    const unsigned half = blockIdx.x & 1u;                 // which half of the row
    const unsigned vbeg = r * ROWVEC + half * HALFVEC;     // first vec4 of this half

    // s_scale: uniform per block. Forward value of sg(clipped - a*g) + a*g,
    // exact op order, no FMA (bit-exact vs numpy).
    const float alpha   = s[r];
    const float clipped = alpha > EPS_F ? alpha : EPS_F;
    const float ag      = __fmul_rn(alpha, g);
    const float ss      = __fadd_rn(__fsub_rn(clipped, ag), ag);

    int count = 0;
    for (unsigned j = threadIdx.x; j < HALFVEC; j += BLOCK) {
        const unsigned i    = vbeg + j;     // global vec4 index
        const unsigned base = i * 4u;       // global element index

        float4a x4  = __builtin_nontemporal_load(reinterpret_cast<const float4a*>(x) + i);
        float4a p4  = __builtin_nontemporal_load(reinterpret_cast<const float4a*>(prev_x_int) + i);
        float4a d4  = __builtin_nontemporal_load(reinterpret_cast<const float4a*>(prev_switch_dir) + i);
        float4a e4  = __builtin_nontemporal_load(reinterpret_cast<const float4a*>(ema_osc) + i);
        float4a fx4 = __builtin_nontemporal_load(reinterpret_cast<const float4a*>(frozen_x_int) + i);
        float4a ex4 = __builtin_nontemporal_load(reinterpret_cast<const float4a*>(ema_x_int) + i);

        bool fzb[4];
        if (mode == 0) {
            unsigned w = __builtin_nontemporal_load(reinterpret_cast<const unsigned*>(frozen) + i);
            fzb[0] = (w & 0x000000FFu) != 0u;
            fzb[1] = (w & 0x0000FF00u) != 0u;
            fzb[2] = (w & 0x00FF0000u) != 0u;
            fzb[3] = (w & 0xFF000000u) != 0u;
        } else if (mode == 1) {
            int4a b = __builtin_nontemporal_load(reinterpret_cast<const int4a*>(frozen) + i);
            fzb[0] = b.x != 0; fzb[1] = b.y != 0; fzb[2] = b.z != 0; fzb[3] = b.w != 0;
        } else {
            float4a b = __builtin_nontemporal_load(reinterpret_cast<const float4a*>(frozen) + i);
            fzb[0] = b.x != 0.0f; fzb[1] = b.y != 0.0f; fzb[2] = b.z != 0.0f; fzb[3] = b.w != 0.0f;
        }

        const float xin[4]  = {x4.x,  x4.y,  x4.z,  x4.w};
        const float pxin[4] = {p4.x,  p4.y,  p4.z,  p4.w};
        const float psdn[4] = {d4.x,  d4.y,  d4.z,  d4.w};
        const float emon[4] = {e4.x,  e4.y,  e4.z,  e4.w};
        const float fxin[4] = {fx4.x, fx4.y, fx4.z, fx4.w};
        const float exin[4] = {ex4.x, ex4.y, ex4.z, ex4.w};

        // Stage 1: xi (forward x_int) per element — shortest deps first.
        float xi[4], delta[4];
        #pragma unroll
        for (int k = 0; k < 4; ++k) {
            float xs = __fdiv_rn(xin[k], ss);                  // IEEE divide == numpy
            float xc = fminf(fmaxf(xs, -8.0f), 7.0f);
            float rr = rintf(xc);                              // half-to-even == np.round
            xi[k]    = fzb[k] ? fxin[k] : rr;
            delta[k] = __fsub_rn(pxin[k], xi[k]);              // exact integer
        }

        // Store out and prev_x_int_new as soon as ready (shorten live ranges)
        __builtin_nontemporal_store((float4a){__fmul_rn(xi[0], ss), __fmul_rn(xi[1], ss),
                                              __fmul_rn(xi[2], ss), __fmul_rn(xi[3], ss)},
                                    reinterpret_cast<float4a*>(o_out) + i);
        __builtin_nontemporal_store((float4a){xi[0], xi[1], xi[2], xi[3]},
                                    reinterpret_cast<float4a*>(o_pxi) + i);

        // Stage 2: switch dir / oscillation
        float sd[4], osc[4];
        #pragma unroll
        for (int k = 0; k < 4; ++k) {
            sd[k]  = (delta[k] > 0.0f) ? 1.0f : ((delta[k] < 0.0f) ? -1.0f : 0.0f);
            osc[k] = (__fmul_rn(psdn[k], sd[k]) == -1.0f) ? 1.0f : 0.0f;
            count += (osc[k] != 0.0f) ? 1 : 0;
        }
        __builtin_nontemporal_store((float4a){(delta[0] != 0.0f) ? sd[0] : psdn[0],
                                              (delta[1] != 0.0f) ? sd[1] : psdn[1],
                                              (delta[2] != 0.0f) ? sd[2] : psdn[2],
                                              (delta[3] != 0.0f) ? sd[3] : psdn[3]},
                                    reinterpret_cast<float4a*>(o_psd) + i);

        // Stage 3: EMA oscillation + freeze decisions (unfused: feeds > 0.01)
        float emo_new[4]; bool fw[4];
        #pragma unroll
        for (int k = 0; k < 4; ++k) {
            emo_new[k] = __fadd_rn(__fmul_rn(0.01f, osc[k]), __fmul_rn(0.99f, emon[k]));
            fw[k]      = emo_new[k] > 0.01f;
        }
        __builtin_nontemporal_store((float4a){emo_new[0], emo_new[1], emo_new[2], emo_new[3]},
                                    reinterpret_cast<float4a*>(o_emo) + i);
        __builtin_nontemporal_store((float4u){(fzb[0] || fw[0]) ? 1.0f : 0.0f,
                                              (fzb[1] || fw[1]) ? 1.0f : 0.0f,
                                              (fzb[2] || fw[2]) ? 1.0f : 0.0f,
                                              (fzb[3] || fw[3]) ? 1.0f : 0.0f},
                                    reinterpret_cast<float4u*>(o_frz + base));
        __builtin_nontemporal_store((float4u){fw[0] ? rintf(exin[0]) : fxin[0],
                                              fw[1] ? rintf(exin[1]) : fxin[1],
                                              fw[2] ? rintf(exin[2]) : fxin[2],
                                              fw[3] ? rintf(exin[3]) : fxin[3]},
                                    reinterpret_cast<float4u*>(o_fxi + base));
        __builtin_nontemporal_store((float4u){
                __fadd_rn(__fmul_rn(0.01f, xi[0]), __fmul_rn(0.99f, exin[0])),
                __fadd_rn(__fmul_rn(0.01f, xi[1]), __fmul_rn(0.99f, exin[1])),
                __fadd_rn(__fmul_rn(0.01f, xi[2]), __fmul_rn(0.99f, exin[2])),
                __fadd_rn(__fmul_rn(0.01f, xi[3]), __fmul_rn(0.99f, exin[3]))},
                                    reinterpret_cast<float4u*>(o_exi + base));
    }

    // exact integer reduction of oscillated count -> one float atomic per block
    for (int off = 32; off > 0; off >>= 1) count += __shfl_down(count, off, 64);
    __shared__ int wsum[BLOCK / 64];
    const int lane = threadIdx.x & 63;
    const int wid  = threadIdx.x >> 6;
    if (lane == 0) wsum[wid] = count;
    __syncthreads();
    if (threadIdx.x == 0) {
        int tot = 0;
        #pragma unroll
        for (int w = 0; w < BLOCK / 64; ++w) tot += wsum[w];
        atomicAdd(o_sum, (float)tot);   // integer-valued, < 2^24 -> exact & deterministic
    }
}

extern "C" void kernel_launch(void* const* d_in, const int* in_sizes, int n_in,
                              void* d_out, int out_size, void* d_ws, size_t ws_size,
                              hipStream_t stream) {
    const float* x   = (const float*)d_in[0];
    const float* s   = (const float*)d_in[1];
    const float* pxi = (const float*)d_in[2];
    const float* psd = (const float*)d_in[3];
    const float* emo = (const float*)d_in[4];
    const void*  frz = d_in[5];
    const float* fxi = (const float*)d_in[6];
    const float* exi = (const float*)d_in[7];
    float* out = (float*)d_out;
    int* mode  = (int*)d_ws;

    const float g = (float)(1.0 / sqrt((double)(7 * 11008)));  // np.float32(1/sqrt(THD_POS*IN))

    hipLaunchKernelGGL(detect_init_kernel, dim3(1), dim3(256), 0, stream,
                       (const unsigned int*)frz, out + (size_t)SUM_OFF, mode);
    hipLaunchKernelGGL(lsq_main_kernel, dim3(GRID), dim3(BLOCK), 0, stream,
                       x, s, pxi, psd, emo, frz, fxi, exi, out, mode, g);
}